// Round 12
// baseline (11834.064 us; speedup 1.0000x reference)
//
#include <hip/hip_runtime.h>
#include <stdint.h>

typedef unsigned short u16;
typedef unsigned int   u32;
typedef unsigned long long u64;
typedef __attribute__((ext_vector_type(4)))  int   i32x4;
typedef __attribute__((ext_vector_type(4)))  float f32x4;
typedef __attribute__((ext_vector_type(8)))  u16   u16x8;
typedef __attribute__((ext_vector_type(8)))  short s16x8;

typedef __attribute__((address_space(3))) char  as3_char;
typedef __attribute__((address_space(3))) i32x4 as3_i32x4;
typedef __attribute__((address_space(3))) s16x8 as3_s16x8;

#define B_    64
#define T_    512
#define DIN_  512
#define H_    1024
#define NBLK_ 256
#define NTHR_ 512

#define HN_BASE_  (64ull*512*1024)
#define CN_BASE_  (HN_BASE_ + 2ull*64*1024)

// ---- workspace layout (bytes) ----
#define WB0_OFF   0ull
#define WB0_SZ    (64ull*64*1536*2)        // 12.6 MB [grp][cd][K]
#define WB1_OFF   (WB0_OFF + WB0_SZ)
#define WB1_SZ    (64ull*64*2048*2)        // 16.8 MB
#define RSLOT_    131072ull                // one [64][1024] bf16 h snapshot
#define NRING_    257
#define RING0_OFF (WB1_OFF + WB1_SZ)
#define RING1_OFF (RING0_OFF + NRING_*RSLOT_)
#define BIAS_OFF  (RING1_OFF + NRING_*RSLOT_)
#define SYNC_OFF  (BIAS_OFF + 32768)       // 64 KB sync region
// total ~96.8 MB (proven budget)

__device__ __forceinline__ u16 f2bf(float f) {   // RNE fp32 -> bf16
  u32 u = __builtin_bit_cast(u32, f);
  return (u16)((u + 0x7FFFu + ((u >> 16) & 1u)) >> 16);
}
__device__ __forceinline__ float sigf(float x) {
  float e = __builtin_amdgcn_exp2f(x * -1.442695041f);
  return __builtin_amdgcn_rcpf(1.0f + e);
}
__device__ __forceinline__ float tanhf_fast(float x) {
  float e = __builtin_amdgcn_exp2f(x * -2.885390082f);
  float r = __builtin_amdgcn_rcpf(1.0f + e);
  return fmaf(2.0f, r, -1.0f);
}

#define VMW(n)  asm volatile("s_waitcnt vmcnt(" #n ")" ::: "memory")

// ============================ prep kernels ============================

__global__ void prep_misc(const float* __restrict__ bih0, const float* __restrict__ bhh0,
                          const float* __restrict__ bih1, const float* __restrict__ bhh1,
                          float* __restrict__ bias, u32* __restrict__ r0z,
                          u32* __restrict__ r1z, u32* __restrict__ sync)
{
  int i = blockIdx.x * 256 + threadIdx.x;        // 1024*256 = 262144 threads
  if (i < 4096) bias[i] = bih0[i] + bhh0[i];
  else if (i < 8192) bias[i] = bih1[i - 4096] + bhh1[i - 4096];
  if (i < 32768) { r0z[i] = 0u; r1z[i] = 0u; }   // zero ring slot 0 (h[-1]=0)
  if (i < 16384) sync[i] = 0u;
}

// W[k][n] fp32 -> Wb[grp][cd][K] bf16, grp=hcol>>4 (64 groups of 16 h-cols),
// cd = gate*16 + (hcol&15).  (round-6/11 proven version, byte-identical)
__global__ void prep_w(const float* __restrict__ Wih0, const float* __restrict__ Whh0,
                       const float* __restrict__ Wih1, const float* __restrict__ Whh1,
                       u16* __restrict__ Wb0, u16* __restrict__ Wb1)
{
  __shared__ u16 tile[64][72];
  const int bid = blockIdx.x;
  const int layer = (bid >= 1536) ? 1 : 0;
  const int lb = layer ? bid - 1536 : bid;
  const int nkt = layer ? 32 : 24;
  const int kt = lb % nkt, nt = lb / nkt;
  const int K = layer ? 2048 : 1536;
  const int xlen = layer ? 1024 : 512;
  const float* Wih = layer ? Wih1 : Wih0;
  const float* Whh = layer ? Whh1 : Whh0;
  u16* Wb = layer ? Wb1 : Wb0;
  const int k0 = kt * 64, n0 = nt * 64;
  const int t = threadIdx.x;
  {
    int kr = t >> 2, ncs = (t & 3) * 16;
    int kk = k0 + kr;
    const float* src = (kk < xlen) ? (Wih + (size_t)kk * 4096)
                                   : (Whh + (size_t)(kk - xlen) * 4096);
    const float* p = src + n0 + ncs;
#pragma unroll
    for (int v = 0; v < 4; ++v) {
      f32x4 f = *(const f32x4*)(p + v * 4);
#pragma unroll
      for (int e = 0; e < 4; ++e) tile[kr][ncs + v*4 + e] = f2bf(f[e]);
    }
  }
  __syncthreads();
  {
    int c = t >> 2;
    int n = n0 + c;
    int gate = n >> 10, hcol = n & 1023;
    int grp = hcol >> 4, cd = gate * 16 + (hcol & 15);
    u16* dstc = Wb + ((size_t)(grp * 64 + cd) * K + k0);
#pragma unroll
    for (int kv = 0; kv < 2; ++kv) {
      int k8 = (t & 3) + 4 * kv;
      u16x8 vv;
#pragma unroll
      for (int e = 0; e < 8; ++e) vv[e] = tile[k8*8 + e][c];
      *(u16x8*)(dstc + k8 * 8) = vv;
    }
  }
}

// ============================ persistent LSTM kernel ============================
// Round-11 geometry (proven 9.16ms): 256 blocks = layer(2) x rowhalf(2) x j(64
// col-groups of 16 h-cols); XCD=j%8; h0/h1 in 257-slot rings (write sc0sc1,
// read plain-cached), flag barrier. NEW (L2-capacity fix): weights jj<32 live
// in LDS (129 KB/block, loaded once; padded col stride 2064 B -> <=2-way bank
// conflict); L2 keeps only the jj>=32 remainder (1.5 MB/XCD -> resident).
// A read DIRECT from global per wave with 8-fragment double-buffered burst
// prefetch (round-10-proven structure, static indices). out stores use nt
// (no L2 write-allocate pollution).

template<int LAYER>
__device__ __forceinline__ void phase(
    const int t, const int i32b, const int tid,
    const float* __restrict__ x,
    const char* __restrict__ wbg,
    const char* __restrict__ rdH0, const char* __restrict__ rdH1,
    char* __restrict__ wrH,
    const float b0, const float b1, const float b2, const float b3,
    const int colg, float& cst,
    float* __restrict__ out, const as3_char* wLds, float* gatesL)
{
  constexpr int K  = LAYER ? 2048 : 1536;
  constexpr int NS = K / 32;               // 48 / 64 k32-slices
  constexpr int JS = 32;                   // LDS-resident slices
  constexpr int NB = NS / 8;               // 6 / 8 bursts
  const int lane = tid & 63, w = tid >> 6;
  const int wm = w >> 2, wn = w & 3;       // 2 m-tiles x 4 n-tiles
  const int l15 = lane & 15, lg = lane >> 4;
  const int arow = i32b + wm * 16 + l15;

  const as3_char* bl = wLds + (size_t)(wn * 16 + l15) * 2064 + lg * 16;
  const char* bg = wbg + (((size_t)(wn * 16 + l15)) * K + lg * 8) * 2;

  auto LOADA = [&](int jj) -> s16x8 {
    if (LAYER == 0) {
      if (jj < 16) {                       // x: fp32 -> bf16 inline (proven r9/10)
        const float* xp = x + ((size_t)arow * T_ + t) * DIN_ + jj * 32 + lg * 8;
        f32x4 u = *(const f32x4*)xp;
        f32x4 v = *(const f32x4*)(xp + 4);
        u16x8 p;
#pragma unroll
        for (int e = 0; e < 4; ++e) { p[e] = f2bf(u[e]); p[4+e] = f2bf(v[e]); }
        return __builtin_bit_cast(s16x8, p);
      }
      return *(const s16x8*)(rdH0 + ((size_t)arow * H_ + (jj - 16) * 32 + lg * 8) * 2);
    } else {
      if (jj < 32)
        return *(const s16x8*)(rdH0 + ((size_t)arow * H_ + jj * 32 + lg * 8) * 2);
      return *(const s16x8*)(rdH1 + ((size_t)arow * H_ + (jj - 32) * 32 + lg * 8) * 2);
    }
  };
  auto LOADB = [&](int jj) -> s16x8 {
    if (jj < JS) return *(const as3_s16x8*)(bl + jj * 64);
    return *(const s16x8*)(bg + jj * 64);
  };

  f32x4 ac0 = {}, ac1 = {};
  s16x8 fa[2][8], fb[2][8];
#pragma unroll
  for (int i = 0; i < 8; ++i) { fa[0][i] = LOADA(i); fb[0][i] = LOADB(i); }
#pragma unroll
  for (int b = 0; b < NB; ++b) {
    if (b + 1 < NB) {
#pragma unroll
      for (int i = 0; i < 8; ++i) {
        fa[(b + 1) & 1][i] = LOADA((b + 1) * 8 + i);
        fb[(b + 1) & 1][i] = LOADB((b + 1) * 8 + i);
      }
    }
#pragma unroll
    for (int i = 0; i < 8; ++i) {
      if (i & 1) ac1 = __builtin_amdgcn_mfma_f32_16x16x32_bf16(fa[b & 1][i], fb[b & 1][i], ac1, 0, 0, 0);
      else       ac0 = __builtin_amdgcn_mfma_f32_16x16x32_bf16(fa[b & 1][i], fb[b & 1][i], ac0, 0, 0, 0);
    }
  }
  f32x4 acc = ac0 + ac1;

  // ---- gates exchange: gatesL[cd(64)][row(36 pad)] fp32 (round-6/11 proven) ----
  *(f32x4*)(gatesL + (size_t)(wn * 16 + l15) * 36 + wm * 16 + lg * 4) = acc;
  __syncthreads();

  // ---- cell update: thread = (hc=tid&15, row=tid>>4), 1 c-elem/thread ----
  {
    const int hc = tid & 15, row = tid >> 4;
    float g0 = gatesL[(size_t)(0 * 16 + hc) * 36 + row];
    float g1 = gatesL[(size_t)(1 * 16 + hc) * 36 + row];
    float g2 = gatesL[(size_t)(2 * 16 + hc) * 36 + row];
    float g3 = gatesL[(size_t)(3 * 16 + hc) * 36 + row];
    float ig = sigf(g0 + b0);
    float fg = sigf(g1 + b1);
    float cg = fmaxf(g2 + b2, 0.0f);
    float og = sigf(g3 + b3);
    float cn = fg * cst + ig * cg;
    cst = cn;
    float h = og * tanhf_fast(cn);
    u32 hb = (u32)f2bf(h);
    int rowg = i32b + row;
    u64 a0 = (u64)(wrH + ((size_t)rowg * H_ + colg) * 2);
    asm volatile("global_store_short %0, %1, off sc0 sc1" :: "v"(a0), "v"(hb) : "memory");
    if (LAYER == 1) {                       // out store: nt (no L2 pollution)
      u64 a1 = (u64)((char*)out + (((size_t)rowg * T_ + t) * H_ + colg) * 4);
      asm volatile("global_store_dword %0, %1, off nt" :: "v"(a1), "v"(h) : "memory");
    }
    if (t == T_ - 1) {
      out[HN_BASE_ + ((size_t)LAYER * 64 + rowg) * H_ + colg] = h;
      out[CN_BASE_ + ((size_t)LAYER * 64 + rowg) * H_ + colg] = cn;
    }
  }
  __syncthreads();                          // gatesL reuse safety across steps
}

__global__ __launch_bounds__(NTHR_, 1) void lstm_persist(
    const float* __restrict__ x, const u16* __restrict__ Wb0, const u16* __restrict__ Wb1,
    char* __restrict__ ring0, char* __restrict__ ring1, const float* __restrict__ bias,
    u32* __restrict__ sync, float* __restrict__ out)
{
  __shared__ __align__(16) char wLdsRaw[64 * 2064];    // 129 KB: jj<32 weight image
  __shared__ __align__(16) float gatesL[64 * 36];      // 9 KB
  as3_char* wLds = (as3_char*)wLdsRaw;
  const int tid = threadIdx.x;
  const int bid = blockIdx.x;
  const int layer = bid >> 7, i = (bid >> 6) & 1, j = bid & 63;
  const int i32b = i * 32;
  const int K = layer ? 2048 : 1536;
  const char* wbg = layer ? ((const char*)Wb1 + (size_t)j * 64 * 2048 * 2)
                          : ((const char*)Wb0 + (size_t)j * 64 * 1536 * 2);

  // ---- one-time: stage jj<32 of the weight slice into LDS (padded stride) ----
#pragma unroll
  for (int c = 0; c < 16; ++c) {
    int ch = c * 512 + tid;
    int cd = ch >> 7, o = ch & 127;        // 128 x 16B chunks per column
    *(as3_i32x4*)(wLds + (size_t)cd * 2064 + o * 16) =
        *(const i32x4*)(wbg + (size_t)cd * K * 2 + o * 16);
  }
  __syncthreads();

  const int colg = j * 16 + (tid & 15);
  float b0, b1, b2, b3;
  {
    const float* bb = bias + layer * 4096;
    b0 = bb[colg]; b1 = bb[1024 + colg]; b2 = bb[2048 + colg]; b3 = bb[3072 + colg];
  }
  float cst = 0.f;
  u32* gflag = sync + 8192;

  for (int s = 0; s <= T_; ++s) {
    const int m0 = s % NRING_;
    const int m1 = (s + 1) % NRING_;
    const int mm = (s >= 1) ? (s - 1) % NRING_ : 0;
    if (layer == 0) {
      if (s < T_)
        phase<0>(s, i32b, tid, x, wbg,
                 ring0 + (size_t)m0 * RSLOT_, nullptr,
                 ring0 + (size_t)m1 * RSLOT_,
                 b0, b1, b2, b3, colg, cst, out, wLds, gatesL);
    } else {
      if (s >= 1)
        phase<1>(s - 1, i32b, tid, x, wbg,
                 ring0 + (size_t)m0 * RSLOT_, ring1 + (size_t)mm * RSLOT_,
                 ring1 + (size_t)m0 * RSLOT_,
                 b0, b1, b2, b3, colg, cst, out, wLds, gatesL);
    }
    // ---- RMW-free flag barrier (round-10/11 proven) ----
    VMW(0);
    __syncthreads();
    if (tid == 0)
      __hip_atomic_store(sync + (size_t)bid * 32, (u32)(s + 1),
                         __ATOMIC_RELAXED, __HIP_MEMORY_SCOPE_AGENT);
    if (bid == 0) {
      if (tid < 256) {
        while (__hip_atomic_load(sync + (size_t)tid * 32,
                                 __ATOMIC_RELAXED, __HIP_MEMORY_SCOPE_AGENT) < (u32)(s + 1))
          __builtin_amdgcn_s_sleep(1);
      }
      __syncthreads();
      if (tid == 0)
        __hip_atomic_store(gflag, (u32)(s + 1),
                           __ATOMIC_RELAXED, __HIP_MEMORY_SCOPE_AGENT);
    } else {
      if (tid == 0) {
        while (__hip_atomic_load(gflag, __ATOMIC_RELAXED,
                                 __HIP_MEMORY_SCOPE_AGENT) < (u32)(s + 1))
          __builtin_amdgcn_s_sleep(1);
      }
      __syncthreads();
    }
  }
}

// ============================ host launch ============================

extern "C" void kernel_launch(void* const* d_in, const int* in_sizes, int n_in,
                              void* d_out, int out_size, void* d_ws, size_t ws_size,
                              hipStream_t stream)
{
  const float* x    = (const float*)d_in[0];
  const float* Wih0 = (const float*)d_in[1];
  const float* bih0 = (const float*)d_in[2];
  const float* Whh0 = (const float*)d_in[3];
  const float* bhh0 = (const float*)d_in[4];
  const float* Wih1 = (const float*)d_in[5];
  const float* bih1 = (const float*)d_in[6];
  const float* Whh1 = (const float*)d_in[7];
  const float* bhh1 = (const float*)d_in[8];

  char* ws = (char*)d_ws;
  u16* Wb0    = (u16*)(ws + WB0_OFF);
  u16* Wb1    = (u16*)(ws + WB1_OFF);
  char* ring0 = ws + RING0_OFF;
  char* ring1 = ws + RING1_OFF;
  float* bias = (float*)(ws + BIAS_OFF);
  u32* sync   = (u32*)(ws + SYNC_OFF);
  float* out  = (float*)d_out;

  prep_misc<<<1024, 256, 0, stream>>>(bih0, bhh0, bih1, bhh1, bias,
                                      (u32*)ring0, (u32*)ring1, sync);
  prep_w<<<3584, 256, 0, stream>>>(Wih0, Whh0, Wih1, Whh1, Wb0, Wb1);
  lstm_persist<<<NBLK_, NTHR_, 0, stream>>>(x, Wb0, Wb1, ring0, ring1, bias, sync, out);
}

// Round 13
// 8684.029 us; speedup vs baseline: 1.3627x; 1.3627x over previous
//
#include <hip/hip_runtime.h>
#include <stdint.h>

typedef unsigned short u16;
typedef unsigned int   u32;
typedef unsigned long long u64;
typedef __attribute__((ext_vector_type(4)))  int   i32x4;
typedef __attribute__((ext_vector_type(4)))  float f32x4;
typedef __attribute__((ext_vector_type(8)))  u16   u16x8;
typedef __attribute__((ext_vector_type(8)))  short s16x8;

typedef __attribute__((address_space(3))) char  as3_char;
typedef __attribute__((address_space(3))) i32x4 as3_i32x4;
typedef __attribute__((address_space(3))) s16x8 as3_s16x8;

#define B_    64
#define T_    512
#define DIN_  512
#define H_    1024
#define NBLK_ 256
#define NTHR_ 512

#define HN_BASE_  (64ull*512*1024)
#define CN_BASE_  (HN_BASE_ + 2ull*64*1024)

// ---- workspace layout (bytes) ----
#define WB0_OFF   0ull
#define WB0_SZ    (64ull*64*1536*2)        // 12.6 MB [grp][cd][K]
#define WB1_OFF   (WB0_OFF + WB0_SZ)
#define WB1_SZ    (64ull*64*2048*2)        // 16.8 MB
#define XT_OFF    (WB1_OFF + WB1_SZ)
#define XT_SZ     (512ull*64*512*2)        // 32 MB  x as bf16 [t][b][d]
#define RSLOT_    131072ull                // one [64][1024] bf16 h snapshot
#define NRING_    129
#define RING0_OFF (XT_OFF + XT_SZ)
#define RING1_OFF (RING0_OFF + NRING_*RSLOT_)
#define BIAS_OFF  (RING1_OFF + NRING_*RSLOT_)
#define SYNC_OFF  (BIAS_OFF + 32768)       // 64 KB sync region
// total ~96.8 MB (proven budget)

__device__ __forceinline__ u16 f2bf(float f) {   // RNE fp32 -> bf16
  u32 u = __builtin_bit_cast(u32, f);
  return (u16)((u + 0x7FFFu + ((u >> 16) & 1u)) >> 16);
}
__device__ __forceinline__ float sigf(float x) {
  float e = __builtin_amdgcn_exp2f(x * -1.442695041f);
  return __builtin_amdgcn_rcpf(1.0f + e);
}
__device__ __forceinline__ float tanhf_fast(float x) {
  float e = __builtin_amdgcn_exp2f(x * -2.885390082f);
  float r = __builtin_amdgcn_rcpf(1.0f + e);
  return fmaf(2.0f, r, -1.0f);
}

#define VMW(n)  asm volatile("s_waitcnt vmcnt(" #n ")" ::: "memory")
#define GLOADNT(dst, a) asm volatile("global_load_dwordx4 %0, %1, off nt" : "=v"(dst) : "v"(a))

// ============================ prep kernels ============================

__global__ void prep_misc(const float* __restrict__ bih0, const float* __restrict__ bhh0,
                          const float* __restrict__ bih1, const float* __restrict__ bhh1,
                          float* __restrict__ bias, u32* __restrict__ r0z,
                          u32* __restrict__ r1z, u32* __restrict__ sync)
{
  int i = blockIdx.x * 256 + threadIdx.x;        // 1024*256 = 262144 threads
  if (i < 4096) bias[i] = bih0[i] + bhh0[i];
  else if (i < 8192) bias[i] = bih1[i - 4096] + bhh1[i - 4096];
  if (i < 32768) { r0z[i] = 0u; r1z[i] = 0u; }   // zero ring slot 0 (h[-1]=0)
  if (i < 16384) sync[i] = 0u;
}

// W[k][n] fp32 -> Wb[grp][cd][K] bf16, grp=hcol>>4, cd=gate*16+(hcol&15).
// (round-6/11 proven, byte-identical)
__global__ void prep_w(const float* __restrict__ Wih0, const float* __restrict__ Whh0,
                       const float* __restrict__ Wih1, const float* __restrict__ Whh1,
                       u16* __restrict__ Wb0, u16* __restrict__ Wb1)
{
  __shared__ u16 tile[64][72];
  const int bid = blockIdx.x;
  const int layer = (bid >= 1536) ? 1 : 0;
  const int lb = layer ? bid - 1536 : bid;
  const int nkt = layer ? 32 : 24;
  const int kt = lb % nkt, nt = lb / nkt;
  const int K = layer ? 2048 : 1536;
  const int xlen = layer ? 1024 : 512;
  const float* Wih = layer ? Wih1 : Wih0;
  const float* Whh = layer ? Whh1 : Whh0;
  u16* Wb = layer ? Wb1 : Wb0;
  const int k0 = kt * 64, n0 = nt * 64;
  const int t = threadIdx.x;
  {
    int kr = t >> 2, ncs = (t & 3) * 16;
    int kk = k0 + kr;
    const float* src = (kk < xlen) ? (Wih + (size_t)kk * 4096)
                                   : (Whh + (size_t)(kk - xlen) * 4096);
    const float* p = src + n0 + ncs;
#pragma unroll
    for (int v = 0; v < 4; ++v) {
      f32x4 f = *(const f32x4*)(p + v * 4);
#pragma unroll
      for (int e = 0; e < 4; ++e) tile[kr][ncs + v*4 + e] = f2bf(f[e]);
    }
  }
  __syncthreads();
  {
    int c = t >> 2;
    int n = n0 + c;
    int gate = n >> 10, hcol = n & 1023;
    int grp = hcol >> 4, cd = gate * 16 + (hcol & 15);
    u16* dstc = Wb + ((size_t)(grp * 64 + cd) * K + k0);
#pragma unroll
    for (int kv = 0; kv < 2; ++kv) {
      int k8 = (t & 3) + 4 * kv;
      u16x8 vv;
#pragma unroll
      for (int e = 0; e < 8; ++e) vv[e] = tile[k8*8 + e][c];
      *(u16x8*)(dstc + k8 * 8) = vv;
    }
  }
}

// x [b][t][d] fp32 -> xT [t][b][d] bf16 (round-1..8 proven)
__global__ void prep_x(const float* __restrict__ x, u16* __restrict__ xT)
{
  int i = blockIdx.x * 256 + threadIdx.x;
  int d16 = (i & 31) << 4;
  int b   = (i >> 5) & 63;
  int tt  = i >> 11;
  const float* s = x + ((size_t)b * T_ + tt) * DIN_ + d16;
  u16* d = xT + ((size_t)tt * B_ + b) * DIN_ + d16;
  f32x4 fa = *(const f32x4*)(s);
  f32x4 fb = *(const f32x4*)(s + 4);
  f32x4 fc = *(const f32x4*)(s + 8);
  f32x4 fd = *(const f32x4*)(s + 12);
  u16x8 o0, o1;
#pragma unroll
  for (int e = 0; e < 4; ++e) {
    o0[e] = f2bf(fa[e]); o0[4+e] = f2bf(fb[e]);
    o1[e] = f2bf(fc[e]); o1[4+e] = f2bf(fd[e]);
  }
  *(u16x8*)d = o0;
  *(u16x8*)(d + 8) = o1;
}

// ============================ persistent LSTM kernel ============================
// Round-11 skeleton (proven 9.16ms): 256 blocks = layer(2) x rowhalf(2) x j(64);
// XCD=j%8; A staged to LDS coalesced; h0/h1 in rings (write sc0sc1, read plain);
// flag barrier. NEW (sub-cliff L2 budget): JS weight jj-slices (13/5 per layer)
// live in LDS -- SAME region for both rowhalf blocks, so per-XCD L2 weights
// shrink 3.67->3.0 MB; x is bf16 (xT) read nt; out stores nt. Total per-XCD
// working set ~3.5 MB < 4 MiB -> weight scan stays resident.

template<int LAYER>
__device__ __forceinline__ void phase(
    const int t, const int i32b, const int tid,
    const u16* __restrict__ xT,
    const char* __restrict__ wbg,
    const char* __restrict__ rdH0, const char* __restrict__ rdH1,
    char* __restrict__ wrH,
    const float b0, const float b1, const float b2, const float b3,
    const int colg, float& cst,
    float* __restrict__ out, as3_char* ldsA, float* gatesL, const as3_char* wlds)
{
  constexpr int K  = LAYER ? 2048 : 1536;
  constexpr int RS = K * 2 + 32;           // padded LDS row stride (bytes)
  constexpr int NS = K / 32;               // k32 slices
  constexpr int JS = LAYER ? 5 : 13;       // LDS-resident weight slices
  const int lane = tid & 63, w = tid >> 6;
  const int l15 = lane & 15, lg = lane >> 4;
  const int wm = w >> 2, wn = w & 3;

  // ---- stage A [32 rows x K] to LDS: issue ALL loads, vmcnt(0), write ----
  if (LAYER == 0) {
    i32x4 sx[4]; int dsx[4];
    i32x4 sh[8]; int dsh[8];
#pragma unroll
    for (int c = 0; c < 4; ++c) {          // x part: k 0..511 (bf16, nt)
      int ch = c * 512 + tid;
      int row = ch >> 6, k16 = ch & 63;
      u64 a = (u64)((const char*)xT + (((size_t)t * B_ + i32b + row) * DIN_ + k16 * 8) * 2);
      GLOADNT(sx[c], a);
      dsx[c] = row * RS + k16 * 16;
    }
#pragma unroll
    for (int c = 0; c < 8; ++c) {          // h0 part: k 512..1535 (plain: L2 dedup)
      int ch = c * 512 + tid;
      int row = ch >> 7, k16 = ch & 127;
      sh[c] = *(const i32x4*)(rdH0 + ((size_t)(i32b + row) * H_ + k16 * 8) * 2);
      dsh[c] = row * RS + (64 + k16) * 16;
    }
    VMW(0);
    __builtin_amdgcn_sched_barrier(0);
#pragma unroll
    for (int c = 0; c < 4; ++c) *(as3_i32x4*)(ldsA + dsx[c]) = sx[c];
#pragma unroll
    for (int c = 0; c < 8; ++c) *(as3_i32x4*)(ldsA + dsh[c]) = sh[c];
  } else {
    i32x4 sh[16]; int dsd[16];
#pragma unroll
    for (int c = 0; c < 8; ++c) {          // h0[t]: k 0..1023
      int ch = c * 512 + tid;
      int row = ch >> 7, k16 = ch & 127;
      sh[c] = *(const i32x4*)(rdH0 + ((size_t)(i32b + row) * H_ + k16 * 8) * 2);
      dsd[c] = row * RS + k16 * 16;
    }
#pragma unroll
    for (int c = 0; c < 8; ++c) {          // h1[t-1]: k 1024..2047
      int ch = c * 512 + tid;
      int row = ch >> 7, k16 = ch & 127;
      sh[8 + c] = *(const i32x4*)(rdH1 + ((size_t)(i32b + row) * H_ + k16 * 8) * 2);
      dsd[8 + c] = row * RS + (128 + k16) * 16;
    }
    VMW(0);
    __builtin_amdgcn_sched_barrier(0);
#pragma unroll
    for (int c = 0; c < 16; ++c) *(as3_i32x4*)(ldsA + dsd[c]) = sh[c];
  }
  __syncthreads();

  // ---- GEMM: one 16x16 tile per wave; B hybrid LDS(jj<JS)/L2 ----
  f32x4 ac0 = {}, ac1 = {};
  const as3_char* arow = ldsA + (size_t)(wm * 16 + l15) * RS;
  const int cd = wn * 16 + l15;
  const as3_char* blb = wlds + (size_t)cd * 64 + ((lg ^ ((cd >> 1) & 3)) << 4);
  const char* bg = wbg + (((size_t)cd) * K + lg * 8) * 2;
#pragma unroll
  for (int jj = 0; jj < NS; jj += 2) {
    s16x8 a0 = *(const as3_s16x8*)(arow + jj * 64 + lg * 16);
    s16x8 a1 = *(const as3_s16x8*)(arow + (jj + 1) * 64 + lg * 16);
    s16x8 bv0, bv1;
    if (jj < JS)     bv0 = *(const as3_s16x8*)(blb + (size_t)jj * 4096);
    else             bv0 = *(const s16x8*)(bg + jj * 64);
    if (jj + 1 < JS) bv1 = *(const as3_s16x8*)(blb + (size_t)(jj + 1) * 4096);
    else             bv1 = *(const s16x8*)(bg + (jj + 1) * 64);
    ac0 = __builtin_amdgcn_mfma_f32_16x16x32_bf16(a0, bv0, ac0, 0, 0, 0);
    ac1 = __builtin_amdgcn_mfma_f32_16x16x32_bf16(a1, bv1, ac1, 0, 0, 0);
  }
  f32x4 acc = ac0 + ac1;

  // ---- gates exchange: gatesL[cd(64)][row(36 pad)] fp32 (proven) ----
  *(f32x4*)(gatesL + (size_t)cd * 36 + wm * 16 + lg * 4) = acc;
  __syncthreads();

  // ---- cell update: thread = (hc=tid&15, row=tid>>4) ----
  {
    const int hc = tid & 15, row = tid >> 4;
    float g0 = gatesL[(size_t)(0 * 16 + hc) * 36 + row];
    float g1 = gatesL[(size_t)(1 * 16 + hc) * 36 + row];
    float g2 = gatesL[(size_t)(2 * 16 + hc) * 36 + row];
    float g3 = gatesL[(size_t)(3 * 16 + hc) * 36 + row];
    float ig = sigf(g0 + b0);
    float fg = sigf(g1 + b1);
    float cg = fmaxf(g2 + b2, 0.0f);
    float og = sigf(g3 + b3);
    float cn = fg * cst + ig * cg;
    cst = cn;
    float h = og * tanhf_fast(cn);
    u32 hb = (u32)f2bf(h);
    int rowg = i32b + row;
    u64 a0 = (u64)(wrH + ((size_t)rowg * H_ + colg) * 2);
    asm volatile("global_store_short %0, %1, off sc0 sc1" :: "v"(a0), "v"(hb) : "memory");
    if (LAYER == 1) {                      // nt: no L2 write-allocate pollution
      u64 a1 = (u64)((char*)out + (((size_t)rowg * T_ + t) * H_ + colg) * 4);
      asm volatile("global_store_dword %0, %1, off nt" :: "v"(a1), "v"(h) : "memory");
    }
    if (t == T_ - 1) {
      out[HN_BASE_ + ((size_t)LAYER * 64 + rowg) * H_ + colg] = h;
      out[CN_BASE_ + ((size_t)LAYER * 64 + rowg) * H_ + colg] = cn;
    }
  }
}

__global__ __launch_bounds__(NTHR_, 1) void lstm_persist(
    const u16* __restrict__ xT, const u16* __restrict__ Wb0, const u16* __restrict__ Wb1,
    char* __restrict__ ring0, char* __restrict__ ring1, const float* __restrict__ bias,
    u32* __restrict__ sync, float* __restrict__ out)
{
  __shared__ __align__(16) char ldsRaw[161792];   // A(max 132096) + gates(9216) + wlds
  as3_char* ldsA = (as3_char*)ldsRaw;
  const int tid = threadIdx.x;
  const int bid = blockIdx.x;
  const int layer = bid >> 7, i = (bid >> 6) & 1, j = bid & 63;
  const int i32b = i * 32;
  const int K = layer ? 2048 : 1536;
  const int Asz = layer ? 132096 : 99328;         // 32 * (K*2+32)
  float* gatesL = (float*)(ldsRaw + Asz);
  as3_char* wlds = (as3_char*)(ldsRaw + Asz + 9216);
  const char* wbg = layer ? ((const char*)Wb1 + (size_t)j * 64 * 2048 * 2)
                          : ((const char*)Wb0 + (size_t)j * 64 * 1536 * 2);

  // ---- one-time: stage jj<JS weight slices into LDS (quad-swizzled) ----
  {
    const int JS = layer ? 5 : 13;
    const int nch = 64 * JS * 4;
    for (int c = tid; c < nch; c += NTHR_) {
      int cd = c / (JS * 4);
      int r  = c - cd * (JS * 4);
      int jj = r >> 2, lg = r & 3;
      i32x4 v = *(const i32x4*)(wbg + ((size_t)cd * K + jj * 32 + lg * 8) * 2);
      *(as3_i32x4*)(wlds + (size_t)jj * 4096 + cd * 64 + ((lg ^ ((cd >> 1) & 3)) << 4)) = v;
    }
  }
  __syncthreads();

  const int colg = j * 16 + (tid & 15);
  float b0, b1, b2, b3;
  {
    const float* bb = bias + layer * 4096;
    b0 = bb[colg]; b1 = bb[1024 + colg]; b2 = bb[2048 + colg]; b3 = bb[3072 + colg];
  }
  float cst = 0.f;
  u32* gflag = sync + 8192;

  for (int s = 0; s <= T_; ++s) {
    const int m0 = s % NRING_;
    const int m1 = (s + 1) % NRING_;
    const int mm = (s >= 1) ? (s - 1) % NRING_ : 0;
    if (layer == 0) {
      if (s < T_)
        phase<0>(s, i32b, tid, xT, wbg,
                 ring0 + (size_t)m0 * RSLOT_, nullptr,
                 ring0 + (size_t)m1 * RSLOT_,
                 b0, b1, b2, b3, colg, cst, out, ldsA, gatesL, wlds);
    } else {
      if (s >= 1)
        phase<1>(s - 1, i32b, tid, xT, wbg,
                 ring0 + (size_t)m0 * RSLOT_, ring1 + (size_t)mm * RSLOT_,
                 ring1 + (size_t)m0 * RSLOT_,
                 b0, b1, b2, b3, colg, cst, out, ldsA, gatesL, wlds);
    }
    // ---- RMW-free flag barrier (round-10/11 proven) ----
    VMW(0);
    __syncthreads();
    if (tid == 0)
      __hip_atomic_store(sync + (size_t)bid * 32, (u32)(s + 1),
                         __ATOMIC_RELAXED, __HIP_MEMORY_SCOPE_AGENT);
    if (bid == 0) {
      if (tid < 256) {
        while (__hip_atomic_load(sync + (size_t)tid * 32,
                                 __ATOMIC_RELAXED, __HIP_MEMORY_SCOPE_AGENT) < (u32)(s + 1))
          __builtin_amdgcn_s_sleep(1);
      }
      __syncthreads();
      if (tid == 0)
        __hip_atomic_store(gflag, (u32)(s + 1),
                           __ATOMIC_RELAXED, __HIP_MEMORY_SCOPE_AGENT);
    } else {
      if (tid == 0) {
        while (__hip_atomic_load(gflag, __ATOMIC_RELAXED,
                                 __HIP_MEMORY_SCOPE_AGENT) < (u32)(s + 1))
          __builtin_amdgcn_s_sleep(1);
      }
      __syncthreads();
    }
  }
}

// ============================ host launch ============================

extern "C" void kernel_launch(void* const* d_in, const int* in_sizes, int n_in,
                              void* d_out, int out_size, void* d_ws, size_t ws_size,
                              hipStream_t stream)
{
  const float* x    = (const float*)d_in[0];
  const float* Wih0 = (const float*)d_in[1];
  const float* bih0 = (const float*)d_in[2];
  const float* Whh0 = (const float*)d_in[3];
  const float* bhh0 = (const float*)d_in[4];
  const float* Wih1 = (const float*)d_in[5];
  const float* bih1 = (const float*)d_in[6];
  const float* Whh1 = (const float*)d_in[7];
  const float* bhh1 = (const float*)d_in[8];

  char* ws = (char*)d_ws;
  u16* Wb0    = (u16*)(ws + WB0_OFF);
  u16* Wb1    = (u16*)(ws + WB1_OFF);
  u16* xT     = (u16*)(ws + XT_OFF);
  char* ring0 = ws + RING0_OFF;
  char* ring1 = ws + RING1_OFF;
  float* bias = (float*)(ws + BIAS_OFF);
  u32* sync   = (u32*)(ws + SYNC_OFF);
  float* out  = (float*)d_out;

  prep_misc<<<1024, 256, 0, stream>>>(bih0, bhh0, bih1, bhh1, bias,
                                      (u32*)ring0, (u32*)ring1, sync);
  prep_w<<<3584, 256, 0, stream>>>(Wih0, Whh0, Wih1, Whh1, Wb0, Wb1);
  prep_x<<<4096, 256, 0, stream>>>(x, xT);
  lstm_persist<<<NBLK_, NTHR_, 0, stream>>>(xT, Wb0, Wb1, ring0, ring1, bias, sync, out);
}

// Round 14
// 8533.331 us; speedup vs baseline: 1.3868x; 1.0177x over previous
//
#include <hip/hip_runtime.h>
#include <stdint.h>

typedef unsigned short u16;
typedef unsigned int   u32;
typedef unsigned long long u64;
typedef __attribute__((ext_vector_type(4)))  int   i32x4;
typedef __attribute__((ext_vector_type(4)))  float f32x4;
typedef __attribute__((ext_vector_type(8)))  u16   u16x8;
typedef __attribute__((ext_vector_type(8)))  short s16x8;

typedef __attribute__((address_space(3))) char  as3_char;
typedef __attribute__((address_space(3))) i32x4 as3_i32x4;
typedef __attribute__((address_space(3))) s16x8 as3_s16x8;

#define B_    64
#define T_    512
#define DIN_  512
#define H_    1024
#define NBLK_ 256
#define NTHR_ 512

#define HN_BASE_  (64ull*512*1024)
#define CN_BASE_  (HN_BASE_ + 2ull*64*1024)

// ---- workspace layout (bytes) ----
#define WB0_OFF   0ull
#define WB0_SZ    (64ull*64*1536*2)        // 12.6 MB [grp][cd][K]
#define WB1_OFF   (WB0_OFF + WB0_SZ)
#define WB1_SZ    (64ull*64*2048*2)        // 16.8 MB
#define XT_OFF    (WB1_OFF + WB1_SZ)
#define XT_SZ     (512ull*64*512*2)        // 32 MB  x as bf16 [t][b][d]
#define RSLOT_    131072ull                // one [64][1024] bf16 h snapshot
#define NRING_    129
#define RING0_OFF (XT_OFF + XT_SZ)
#define RING1_OFF (RING0_OFF + NRING_*RSLOT_)
#define BIAS_OFF  (RING1_OFF + NRING_*RSLOT_)
#define SYNC_OFF  (BIAS_OFF + 32768)       // 64 KB sync region
// total ~96.8 MB (proven budget)

__device__ __forceinline__ u16 f2bf(float f) {   // RNE fp32 -> bf16
  u32 u = __builtin_bit_cast(u32, f);
  return (u16)((u + 0x7FFFu + ((u >> 16) & 1u)) >> 16);
}
__device__ __forceinline__ float sigf(float x) {
  float e = __builtin_amdgcn_exp2f(x * -1.442695041f);
  return __builtin_amdgcn_rcpf(1.0f + e);
}
__device__ __forceinline__ float tanhf_fast(float x) {
  float e = __builtin_amdgcn_exp2f(x * -2.885390082f);
  float r = __builtin_amdgcn_rcpf(1.0f + e);
  return fmaf(2.0f, r, -1.0f);
}

#define VMW(n)  asm volatile("s_waitcnt vmcnt(" #n ")" ::: "memory")

// ============================ prep kernels ============================

__global__ void prep_misc(const float* __restrict__ bih0, const float* __restrict__ bhh0,
                          const float* __restrict__ bih1, const float* __restrict__ bhh1,
                          float* __restrict__ bias, u32* __restrict__ r0z,
                          u32* __restrict__ r1z, u32* __restrict__ sync)
{
  int i = blockIdx.x * 256 + threadIdx.x;        // 1024*256 = 262144 threads
  if (i < 4096) bias[i] = bih0[i] + bhh0[i];
  else if (i < 8192) bias[i] = bih1[i - 4096] + bhh1[i - 4096];
  if (i < 32768) { r0z[i] = 0u; r1z[i] = 0u; }   // zero ring slot 0 (h[-1]=0)
  if (i < 16384) sync[i] = 0u;
}

// W[k][n] fp32 -> Wb[grp][cd][K] bf16, grp=hcol>>4, cd=gate*16+(hcol&15).
// (round-6/11/13 proven, byte-identical)
__global__ void prep_w(const float* __restrict__ Wih0, const float* __restrict__ Whh0,
                       const float* __restrict__ Wih1, const float* __restrict__ Whh1,
                       u16* __restrict__ Wb0, u16* __restrict__ Wb1)
{
  __shared__ u16 tile[64][72];
  const int bid = blockIdx.x;
  const int layer = (bid >= 1536) ? 1 : 0;
  const int lb = layer ? bid - 1536 : bid;
  const int nkt = layer ? 32 : 24;
  const int kt = lb % nkt, nt = lb / nkt;
  const int K = layer ? 2048 : 1536;
  const int xlen = layer ? 1024 : 512;
  const float* Wih = layer ? Wih1 : Wih0;
  const float* Whh = layer ? Whh1 : Whh0;
  u16* Wb = layer ? Wb1 : Wb0;
  const int k0 = kt * 64, n0 = nt * 64;
  const int t = threadIdx.x;
  {
    int kr = t >> 2, ncs = (t & 3) * 16;
    int kk = k0 + kr;
    const float* src = (kk < xlen) ? (Wih + (size_t)kk * 4096)
                                   : (Whh + (size_t)(kk - xlen) * 4096);
    const float* p = src + n0 + ncs;
#pragma unroll
    for (int v = 0; v < 4; ++v) {
      f32x4 f = *(const f32x4*)(p + v * 4);
#pragma unroll
      for (int e = 0; e < 4; ++e) tile[kr][ncs + v*4 + e] = f2bf(f[e]);
    }
  }
  __syncthreads();
  {
    int c = t >> 2;
    int n = n0 + c;
    int gate = n >> 10, hcol = n & 1023;
    int grp = hcol >> 4, cd = gate * 16 + (hcol & 15);
    u16* dstc = Wb + ((size_t)(grp * 64 + cd) * K + k0);
#pragma unroll
    for (int kv = 0; kv < 2; ++kv) {
      int k8 = (t & 3) + 4 * kv;
      u16x8 vv;
#pragma unroll
      for (int e = 0; e < 8; ++e) vv[e] = tile[k8*8 + e][c];
      *(u16x8*)(dstc + k8 * 8) = vv;
    }
  }
}

// x [b][t][d] fp32 -> xT [t][b][d] bf16 (round-1..8/13 proven)
__global__ void prep_x(const float* __restrict__ x, u16* __restrict__ xT)
{
  int i = blockIdx.x * 256 + threadIdx.x;
  int d16 = (i & 31) << 4;
  int b   = (i >> 5) & 63;
  int tt  = i >> 11;
  const float* s = x + ((size_t)b * T_ + tt) * DIN_ + d16;
  u16* d = xT + ((size_t)tt * B_ + b) * DIN_ + d16;
  f32x4 fa = *(const f32x4*)(s);
  f32x4 fb = *(const f32x4*)(s + 4);
  f32x4 fc = *(const f32x4*)(s + 8);
  f32x4 fd = *(const f32x4*)(s + 12);
  u16x8 o0, o1;
#pragma unroll
  for (int e = 0; e < 4; ++e) {
    o0[e] = f2bf(fa[e]); o0[4+e] = f2bf(fb[e]);
    o1[e] = f2bf(fc[e]); o1[4+e] = f2bf(fd[e]);
  }
  *(u16x8*)d = o0;
  *(u16x8*)(d + 8) = o1;
}

// ============================ persistent LSTM kernel ============================
// Round-13 skeleton (proven 8.68ms): 256 blocks = layer(2) x rowhalf(2) x j(64);
// XCD=j%8; A staged to LDS coalesced; JS weight slices in LDS (13/5), rest L2;
// h0/h1 in rings (write sc0sc1, read plain). CHANGES vs r13:
//  1. Split DIRECT-POLL barriers: dependency graph factors into 2 independent
//     row-groups; within one, layer0 depends only on layer0. Each block's
//     threads 0..127 poll the 128 relevant arrival slots directly (no block-0
//     funnel, no gflag). Layer0 additionally lag-capped to layer1+64 (< ring
//     depth 129 -> no WAR).
//  2. x loads PLAIN (nt dropped): 64 j-blocks share x -> L2 dedup.

template<int LAYER>
__device__ __forceinline__ void phase(
    const int t, const int i32b, const int tid,
    const u16* __restrict__ xT,
    const char* __restrict__ wbg,
    const char* __restrict__ rdH0, const char* __restrict__ rdH1,
    char* __restrict__ wrH,
    const float b0, const float b1, const float b2, const float b3,
    const int colg, float& cst,
    float* __restrict__ out, as3_char* ldsA, float* gatesL, const as3_char* wlds)
{
  constexpr int K  = LAYER ? 2048 : 1536;
  constexpr int RS = K * 2 + 32;           // padded LDS row stride (bytes)
  constexpr int NS = K / 32;               // k32 slices
  constexpr int JS = LAYER ? 5 : 13;       // LDS-resident weight slices
  const int lane = tid & 63, w = tid >> 6;
  const int l15 = lane & 15, lg = lane >> 4;
  const int wm = w >> 2, wn = w & 3;

  // ---- stage A [32 rows x K] to LDS: issue ALL loads, vmcnt(0), write ----
  if (LAYER == 0) {
    i32x4 sx[4]; int dsx[4];
    i32x4 sh[8]; int dsh[8];
#pragma unroll
    for (int c = 0; c < 4; ++c) {          // x part: k 0..511 (bf16, plain: L2 dedup)
      int ch = c * 512 + tid;
      int row = ch >> 6, k16 = ch & 63;
      sx[c] = *(const i32x4*)((const char*)xT +
                (((size_t)t * B_ + i32b + row) * DIN_ + k16 * 8) * 2);
      dsx[c] = row * RS + k16 * 16;
    }
#pragma unroll
    for (int c = 0; c < 8; ++c) {          // h0 part: k 512..1535 (plain: L2 dedup)
      int ch = c * 512 + tid;
      int row = ch >> 7, k16 = ch & 127;
      sh[c] = *(const i32x4*)(rdH0 + ((size_t)(i32b + row) * H_ + k16 * 8) * 2);
      dsh[c] = row * RS + (64 + k16) * 16;
    }
    VMW(0);
    __builtin_amdgcn_sched_barrier(0);
#pragma unroll
    for (int c = 0; c < 4; ++c) *(as3_i32x4*)(ldsA + dsx[c]) = sx[c];
#pragma unroll
    for (int c = 0; c < 8; ++c) *(as3_i32x4*)(ldsA + dsh[c]) = sh[c];
  } else {
    i32x4 sh[16]; int dsd[16];
#pragma unroll
    for (int c = 0; c < 8; ++c) {          // h0[t]: k 0..1023
      int ch = c * 512 + tid;
      int row = ch >> 7, k16 = ch & 127;
      sh[c] = *(const i32x4*)(rdH0 + ((size_t)(i32b + row) * H_ + k16 * 8) * 2);
      dsd[c] = row * RS + k16 * 16;
    }
#pragma unroll
    for (int c = 0; c < 8; ++c) {          // h1[t-1]: k 1024..2047
      int ch = c * 512 + tid;
      int row = ch >> 7, k16 = ch & 127;
      sh[8 + c] = *(const i32x4*)(rdH1 + ((size_t)(i32b + row) * H_ + k16 * 8) * 2);
      dsd[8 + c] = row * RS + (128 + k16) * 16;
    }
    VMW(0);
    __builtin_amdgcn_sched_barrier(0);
#pragma unroll
    for (int c = 0; c < 16; ++c) *(as3_i32x4*)(ldsA + dsd[c]) = sh[c];
  }
  __syncthreads();

  // ---- GEMM: one 16x16 tile per wave; B hybrid LDS(jj<JS)/L2 ----
  f32x4 ac0 = {}, ac1 = {};
  const as3_char* arow = ldsA + (size_t)(wm * 16 + l15) * RS;
  const int cd = wn * 16 + l15;
  const as3_char* blb = wlds + (size_t)cd * 64 + ((lg ^ ((cd >> 1) & 3)) << 4);
  const char* bg = wbg + (((size_t)cd) * K + lg * 8) * 2;
#pragma unroll
  for (int jj = 0; jj < NS; jj += 2) {
    s16x8 a0 = *(const as3_s16x8*)(arow + jj * 64 + lg * 16);
    s16x8 a1 = *(const as3_s16x8*)(arow + (jj + 1) * 64 + lg * 16);
    s16x8 bv0, bv1;
    if (jj < JS)     bv0 = *(const as3_s16x8*)(blb + (size_t)jj * 4096);
    else             bv0 = *(const s16x8*)(bg + jj * 64);
    if (jj + 1 < JS) bv1 = *(const as3_s16x8*)(blb + (size_t)(jj + 1) * 4096);
    else             bv1 = *(const s16x8*)(bg + (jj + 1) * 64);
    ac0 = __builtin_amdgcn_mfma_f32_16x16x32_bf16(a0, bv0, ac0, 0, 0, 0);
    ac1 = __builtin_amdgcn_mfma_f32_16x16x32_bf16(a1, bv1, ac1, 0, 0, 0);
  }
  f32x4 acc = ac0 + ac1;

  // ---- gates exchange: gatesL[cd(64)][row(36 pad)] fp32 (proven) ----
  *(f32x4*)(gatesL + (size_t)cd * 36 + wm * 16 + lg * 4) = acc;
  __syncthreads();

  // ---- cell update: thread = (hc=tid&15, row=tid>>4) ----
  {
    const int hc = tid & 15, row = tid >> 4;
    float g0 = gatesL[(size_t)(0 * 16 + hc) * 36 + row];
    float g1 = gatesL[(size_t)(1 * 16 + hc) * 36 + row];
    float g2 = gatesL[(size_t)(2 * 16 + hc) * 36 + row];
    float g3 = gatesL[(size_t)(3 * 16 + hc) * 36 + row];
    float ig = sigf(g0 + b0);
    float fg = sigf(g1 + b1);
    float cg = fmaxf(g2 + b2, 0.0f);
    float og = sigf(g3 + b3);
    float cn = fg * cst + ig * cg;
    cst = cn;
    float h = og * tanhf_fast(cn);
    u32 hb = (u32)f2bf(h);
    int rowg = i32b + row;
    u64 a0 = (u64)(wrH + ((size_t)rowg * H_ + colg) * 2);
    asm volatile("global_store_short %0, %1, off sc0 sc1" :: "v"(a0), "v"(hb) : "memory");
    if (LAYER == 1) {                      // nt: no L2 write-allocate pollution
      u64 a1 = (u64)((char*)out + (((size_t)rowg * T_ + t) * H_ + colg) * 4);
      asm volatile("global_store_dword %0, %1, off nt" :: "v"(a1), "v"(h) : "memory");
    }
    if (t == T_ - 1) {
      out[HN_BASE_ + ((size_t)LAYER * 64 + rowg) * H_ + colg] = h;
      out[CN_BASE_ + ((size_t)LAYER * 64 + rowg) * H_ + colg] = cn;
    }
  }
}

__global__ __launch_bounds__(NTHR_, 1) void lstm_persist(
    const u16* __restrict__ xT, const u16* __restrict__ Wb0, const u16* __restrict__ Wb1,
    char* __restrict__ ring0, char* __restrict__ ring1, const float* __restrict__ bias,
    u32* __restrict__ sync, float* __restrict__ out)
{
  __shared__ __align__(16) char ldsRaw[161792];   // A(max 132096) + gates(9216) + wlds
  as3_char* ldsA = (as3_char*)ldsRaw;
  const int tid = threadIdx.x;
  const int bid = blockIdx.x;
  const int layer = bid >> 7, i = (bid >> 6) & 1, j = bid & 63;
  const int i32b = i * 32;
  const int K = layer ? 2048 : 1536;
  const int Asz = layer ? 132096 : 99328;         // 32 * (K*2+32)
  float* gatesL = (float*)(ldsRaw + Asz);
  as3_char* wlds = (as3_char*)(ldsRaw + Asz + 9216);
  const char* wbg = layer ? ((const char*)Wb1 + (size_t)j * 64 * 2048 * 2)
                          : ((const char*)Wb0 + (size_t)j * 64 * 1536 * 2);

  // ---- one-time: stage jj<JS weight slices into LDS (quad-swizzled) ----
  {
    const int JS = layer ? 5 : 13;
    const int nch = 64 * JS * 4;
    for (int c = tid; c < nch; c += NTHR_) {
      int cd = c / (JS * 4);
      int r  = c - cd * (JS * 4);
      int jj = r >> 2, lg = r & 3;
      i32x4 v = *(const i32x4*)(wbg + ((size_t)cd * K + jj * 32 + lg * 8) * 2);
      *(as3_i32x4*)(wlds + (size_t)jj * 4096 + cd * 64 + ((lg ^ ((cd >> 1) & 3)) << 4)) = v;
    }
  }
  __syncthreads();

  const int colg = j * 16 + (tid & 15);
  float b0, b1, b2, b3;
  {
    const float* bb = bias + layer * 4096;
    b0 = bb[colg]; b1 = bb[1024 + colg]; b2 = bb[2048 + colg]; b3 = bb[3072 + colg];
  }
  float cst = 0.f;

  for (int s = 0; s <= T_; ++s) {
    const int m0 = s % NRING_;
    const int m1 = (s + 1) % NRING_;
    const int mm = (s >= 1) ? (s - 1) % NRING_ : 0;
    if (layer == 0) {
      if (s < T_)
        phase<0>(s, i32b, tid, xT, wbg,
                 ring0 + (size_t)m0 * RSLOT_, nullptr,
                 ring0 + (size_t)m1 * RSLOT_,
                 b0, b1, b2, b3, colg, cst, out, ldsA, gatesL, wlds);
    } else {
      if (s >= 1)
        phase<1>(s - 1, i32b, tid, xT, wbg,
                 ring0 + (size_t)m0 * RSLOT_, ring1 + (size_t)mm * RSLOT_,
                 ring1 + (size_t)m0 * RSLOT_,
                 b0, b1, b2, b3, colg, cst, out, ldsA, gatesL, wlds);
    }
    // ---- split direct-poll barrier (row-group local) ----
    VMW(0);                                  // drain data stores (incl. sc0sc1)
    __syncthreads();
    if (tid == 0)
      __hip_atomic_store(sync + (size_t)bid * 32, (u32)(s + 1),
                         __ATOMIC_RELAXED, __HIP_MEMORY_SCOPE_AGENT);
    {
      // layer0 blocks: need layer0-same-i >= s+1, layer1-same-i >= s+1-64 (lag cap)
      // layer1 blocks: need layer0-same-i >= s+1, layer1-same-i >= s+1
      const u32 tgtL1 = layer ? (u32)(s + 1)
                              : (u32)((s + 1 > 64) ? (s + 1 - 64) : 0);
      if (tid < 128) {
        const int grp = tid >> 6;            // 0: poll layer0 slots, 1: layer1 slots
        const int jp  = tid & 63;
        const u32 tgt = grp ? tgtL1 : (u32)(s + 1);
        if (tgt) {
          u32* slot = sync + ((size_t)(grp * 128 + i * 64 + jp)) * 32;
          while (__hip_atomic_load(slot, __ATOMIC_RELAXED,
                                   __HIP_MEMORY_SCOPE_AGENT) < tgt)
            __builtin_amdgcn_s_sleep(2);
        }
      }
      __syncthreads();
    }
  }
}

// ============================ host launch ============================

extern "C" void kernel_launch(void* const* d_in, const int* in_sizes, int n_in,
                              void* d_out, int out_size, void* d_ws, size_t ws_size,
                              hipStream_t stream)
{
  const float* x    = (const float*)d_in[0];
  const float* Wih0 = (const float*)d_in[1];
  const float* bih0 = (const float*)d_in[2];
  const float* Whh0 = (const float*)d_in[3];
  const float* bhh0 = (const float*)d_in[4];
  const float* Wih1 = (const float*)d_in[5];
  const float* bih1 = (const float*)d_in[6];
  const float* Whh1 = (const float*)d_in[7];
  const float* bhh1 = (const float*)d_in[8];

  char* ws = (char*)d_ws;
  u16* Wb0    = (u16*)(ws + WB0_OFF);
  u16* Wb1    = (u16*)(ws + WB1_OFF);
  u16* xT     = (u16*)(ws + XT_OFF);
  char* ring0 = ws + RING0_OFF;
  char* ring1 = ws + RING1_OFF;
  float* bias = (float*)(ws + BIAS_OFF);
  u32* sync   = (u32*)(ws + SYNC_OFF);
  float* out  = (float*)d_out;

  prep_misc<<<1024, 256, 0, stream>>>(bih0, bhh0, bih1, bhh1, bias,
                                      (u32*)ring0, (u32*)ring1, sync);
  prep_w<<<3584, 256, 0, stream>>>(Wih0, Whh0, Wih1, Whh1, Wb0, Wb1);
  prep_x<<<4096, 256, 0, stream>>>(x, xT);
  lstm_persist<<<NBLK_, NTHR_, 0, stream>>>(xT, Wb0, Wb1, ring0, ring1, bias, sync, out);
}

// Round 15
// 6475.265 us; speedup vs baseline: 1.8276x; 1.3178x over previous
//
#include <hip/hip_runtime.h>
#include <stdint.h>

typedef unsigned short u16;
typedef unsigned int   u32;
typedef unsigned long long u64;
typedef __attribute__((ext_vector_type(4)))  int   i32x4;
typedef __attribute__((ext_vector_type(4)))  float f32x4;
typedef __attribute__((ext_vector_type(8)))  u16   u16x8;
typedef __attribute__((ext_vector_type(8)))  short s16x8;

typedef __attribute__((address_space(3))) char  as3_char;
typedef __attribute__((address_space(3))) i32x4 as3_i32x4;
typedef __attribute__((address_space(3))) s16x8 as3_s16x8;

#define B_    64
#define T_    512
#define DIN_  512
#define H_    1024
#define NBLK_ 256
#define NTHR_ 512

#define HN_BASE_  (64ull*512*1024)
#define CN_BASE_  (HN_BASE_ + 2ull*64*1024)

// ---- workspace layout (bytes) ----
#define WB0_OFF   0ull
#define WB0_SZ    (64ull*64*1536*2)        // 12.6 MB [grp][cd][K]
#define WB1_OFF   (WB0_OFF + WB0_SZ)
#define WB1_SZ    (64ull*64*2048*2)        // 16.8 MB
#define XT_OFF    (WB1_OFF + WB1_SZ)
#define XT_SZ     (512ull*64*512*2)        // 32 MB  x as bf16 [t][b][d]
#define RSLOT_    131072ull                // one [64][1024] bf16 h snapshot
#define NRING_    129
#define RING0_OFF (XT_OFF + XT_SZ)
#define RING1_OFF (RING0_OFF + NRING_*RSLOT_)
#define BIAS_OFF  (RING1_OFF + NRING_*RSLOT_)
#define SYNC_OFF  (BIAS_OFF + 32768)       // 64 KB sync region
// total ~96.8 MB (proven budget)

__device__ __forceinline__ u16 f2bf(float f) {   // RNE fp32 -> bf16
  u32 u = __builtin_bit_cast(u32, f);
  return (u16)((u + 0x7FFFu + ((u >> 16) & 1u)) >> 16);
}
__device__ __forceinline__ float sigf(float x) {
  float e = __builtin_amdgcn_exp2f(x * -1.442695041f);
  return __builtin_amdgcn_rcpf(1.0f + e);
}
__device__ __forceinline__ float tanhf_fast(float x) {
  float e = __builtin_amdgcn_exp2f(x * -2.885390082f);
  float r = __builtin_amdgcn_rcpf(1.0f + e);
  return fmaf(2.0f, r, -1.0f);
}

#define VMW(n)  asm volatile("s_waitcnt vmcnt(" #n ")" ::: "memory")

// ============================ prep kernels ============================

__global__ void prep_misc(const float* __restrict__ bih0, const float* __restrict__ bhh0,
                          const float* __restrict__ bih1, const float* __restrict__ bhh1,
                          float* __restrict__ bias, u32* __restrict__ r0z,
                          u32* __restrict__ r1z, u32* __restrict__ sync)
{
  int i = blockIdx.x * 256 + threadIdx.x;        // 1024*256 = 262144 threads
  if (i < 4096) bias[i] = bih0[i] + bhh0[i];
  else if (i < 8192) bias[i] = bih1[i - 4096] + bhh1[i - 4096];
  if (i < 32768) { r0z[i] = 0u; r1z[i] = 0u; }   // zero ring slot 0 (h[-1]=0)
  if (i < 16384) sync[i] = 0u;
}

// W[k][n] fp32 -> Wb[grp][cd][K] bf16, grp=hcol>>4, cd=gate*16+(hcol&15).
// (round-6/11/13/14 proven, byte-identical)
__global__ void prep_w(const float* __restrict__ Wih0, const float* __restrict__ Whh0,
                       const float* __restrict__ Wih1, const float* __restrict__ Whh1,
                       u16* __restrict__ Wb0, u16* __restrict__ Wb1)
{
  __shared__ u16 tile[64][72];
  const int bid = blockIdx.x;
  const int layer = (bid >= 1536) ? 1 : 0;
  const int lb = layer ? bid - 1536 : bid;
  const int nkt = layer ? 32 : 24;
  const int kt = lb % nkt, nt = lb / nkt;
  const int K = layer ? 2048 : 1536;
  const int xlen = layer ? 1024 : 512;
  const float* Wih = layer ? Wih1 : Wih0;
  const float* Whh = layer ? Whh1 : Whh0;
  u16* Wb = layer ? Wb1 : Wb0;
  const int k0 = kt * 64, n0 = nt * 64;
  const int t = threadIdx.x;
  {
    int kr = t >> 2, ncs = (t & 3) * 16;
    int kk = k0 + kr;
    const float* src = (kk < xlen) ? (Wih + (size_t)kk * 4096)
                                   : (Whh + (size_t)(kk - xlen) * 4096);
    const float* p = src + n0 + ncs;
#pragma unroll
    for (int v = 0; v < 4; ++v) {
      f32x4 f = *(const f32x4*)(p + v * 4);
#pragma unroll
      for (int e = 0; e < 4; ++e) tile[kr][ncs + v*4 + e] = f2bf(f[e]);
    }
  }
  __syncthreads();
  {
    int c = t >> 2;
    int n = n0 + c;
    int gate = n >> 10, hcol = n & 1023;
    int grp = hcol >> 4, cd = gate * 16 + (hcol & 15);
    u16* dstc = Wb + ((size_t)(grp * 64 + cd) * K + k0);
#pragma unroll
    for (int kv = 0; kv < 2; ++kv) {
      int k8 = (t & 3) + 4 * kv;
      u16x8 vv;
#pragma unroll
      for (int e = 0; e < 8; ++e) vv[e] = tile[k8*8 + e][c];
      *(u16x8*)(dstc + k8 * 8) = vv;
    }
  }
}

// x [b][t][d] fp32 -> xT [t][b][d] bf16 (proven)
__global__ void prep_x(const float* __restrict__ x, u16* __restrict__ xT)
{
  int i = blockIdx.x * 256 + threadIdx.x;
  int d16 = (i & 31) << 4;
  int b   = (i >> 5) & 63;
  int tt  = i >> 11;
  const float* s = x + ((size_t)b * T_ + tt) * DIN_ + d16;
  u16* d = xT + ((size_t)tt * B_ + b) * DIN_ + d16;
  f32x4 fa = *(const f32x4*)(s);
  f32x4 fb = *(const f32x4*)(s + 4);
  f32x4 fc = *(const f32x4*)(s + 8);
  f32x4 fd = *(const f32x4*)(s + 12);
  u16x8 o0, o1;
#pragma unroll
  for (int e = 0; e < 4; ++e) {
    o0[e] = f2bf(fa[e]); o0[4+e] = f2bf(fb[e]);
    o1[e] = f2bf(fc[e]); o1[4+e] = f2bf(fd[e]);
  }
  *(u16x8*)d = o0;
  *(u16x8*)(d + 8) = o1;
}

// ============================ persistent LSTM kernel ============================
// Round-14 skeleton (proven 8.53ms): 256 blocks = layer(2) x rowhalf(2) x j(64);
// XCD=j%8; rings (write sc0sc1, read plain); split direct-poll barrier.
// NEW: A staged in TWO K-halves through one 65KB buffer (layer1: h0|h1;
// layer0: x|h0). Half2 loads issued BEFORE GEMM half1 (latency hidden).
// Freed LDS doubles the LDS-resident weights: JS 13/5 -> 21/21, cutting the
// per-XCD L2 weight stream to 2.2 MB (< 4 MiB with streams) -> resident.
// All staging is plain-C loads (compiler-exact waitcnt; r5 lesson).

template<int LAYER>
__device__ __forceinline__ void phase(
    const int t, const int i32b, const int tid,
    const u16* __restrict__ xT,
    const char* __restrict__ wbg,
    const char* __restrict__ rdH0, const char* __restrict__ rdH1,
    char* __restrict__ wrH,
    const float b0, const float b1, const float b2, const float b3,
    const int colg, float& cst,
    float* __restrict__ out, as3_char* ldsA, float* gatesL, const as3_char* wlds)
{
  constexpr int K   = LAYER ? 2048 : 1536;
  constexpr int RS2 = 1024 * 2 + 32;       // 2080: padded row stride (K-half)
  constexpr int NS1 = LAYER ? 32 : 16;     // half1 slices (L1: h0 / L0: x)
  constexpr int NS2 = 32;                  // half2 slices (L1: h1 / L0: h0)
  constexpr int JB2 = LAYER ? 32 : 16;     // global jj base of half2
  constexpr int JS  = 21;                  // LDS-resident weight slices
  const int lane = tid & 63, w = tid >> 6;
  const int l15 = lane & 15, lg = lane >> 4;
  const int wm = w >> 2, wn = w & 3;

  // ---- stage half1 into LDS (plain C: compiler schedules loads + waits) ----
  if (LAYER == 0) {
#pragma unroll
    for (int c = 0; c < 4; ++c) {          // x: 32 rows x 512 bf16
      int ch = c * 512 + tid;
      int row = ch >> 6, k16 = ch & 63;
      i32x4 v = *(const i32x4*)((const char*)xT +
                  (((size_t)t * B_ + i32b + row) * DIN_ + k16 * 8) * 2);
      *(as3_i32x4*)(ldsA + row * RS2 + k16 * 16) = v;
    }
  } else {
#pragma unroll
    for (int c = 0; c < 8; ++c) {          // h0[t]: 32 rows x 1024 bf16
      int ch = c * 512 + tid;
      int row = ch >> 7, k16 = ch & 127;
      i32x4 v = *(const i32x4*)(rdH0 + ((size_t)(i32b + row) * H_ + k16 * 8) * 2);
      *(as3_i32x4*)(ldsA + row * RS2 + k16 * 16) = v;
    }
  }
  // ---- issue half2 loads into registers (hoisted: latency hides under GEMM1) ----
  i32x4 s2[8]; int d2[8];
  {
    const char* src2 = LAYER ? rdH1 : rdH0;
#pragma unroll
    for (int c = 0; c < 8; ++c) {          // 32 rows x 1024 bf16
      int ch = c * 512 + tid;
      int row = ch >> 7, k16 = ch & 127;
      s2[c] = *(const i32x4*)(src2 + ((size_t)(i32b + row) * H_ + k16 * 8) * 2);
      d2[c] = row * RS2 + k16 * 16;
    }
  }
  __syncthreads();

  // ---- GEMM half1 ----
  f32x4 ac0 = {}, ac1 = {};
  const as3_char* arow = ldsA + (size_t)(wm * 16 + l15) * RS2;
  const int cd = wn * 16 + l15;
  const as3_char* blb = wlds + (size_t)cd * 64 + ((lg ^ ((cd >> 1) & 3)) << 4);
  const char* bg = wbg + (((size_t)cd) * K + lg * 8) * 2;
#pragma unroll
  for (int jj = 0; jj < NS1; jj += 2) {
    s16x8 a0 = *(const as3_s16x8*)(arow + jj * 64 + lg * 16);
    s16x8 a1 = *(const as3_s16x8*)(arow + (jj + 1) * 64 + lg * 16);
    s16x8 bv0, bv1;
    if (jj < JS)     bv0 = *(const as3_s16x8*)(blb + (size_t)jj * 4096);
    else             bv0 = *(const s16x8*)(bg + jj * 64);
    if (jj + 1 < JS) bv1 = *(const as3_s16x8*)(blb + (size_t)(jj + 1) * 4096);
    else             bv1 = *(const s16x8*)(bg + (jj + 1) * 64);
    ac0 = __builtin_amdgcn_mfma_f32_16x16x32_bf16(a0, bv0, ac0, 0, 0, 0);
    ac1 = __builtin_amdgcn_mfma_f32_16x16x32_bf16(a1, bv1, ac1, 0, 0, 0);
  }
  __syncthreads();                         // all waves done reading half1

  // ---- write half2 to LDS (compiler waits s2 here), then GEMM half2 ----
#pragma unroll
  for (int c = 0; c < 8; ++c) *(as3_i32x4*)(ldsA + d2[c]) = s2[c];
  __syncthreads();
#pragma unroll
  for (int l = 0; l < NS2; l += 2) {
    const int g0 = JB2 + l, g1 = JB2 + l + 1;
    s16x8 a0 = *(const as3_s16x8*)(arow + l * 64 + lg * 16);
    s16x8 a1 = *(const as3_s16x8*)(arow + (l + 1) * 64 + lg * 16);
    s16x8 bv0, bv1;
    if (g0 < JS)     bv0 = *(const as3_s16x8*)(blb + (size_t)g0 * 4096);
    else             bv0 = *(const s16x8*)(bg + g0 * 64);
    if (g1 < JS)     bv1 = *(const as3_s16x8*)(blb + (size_t)g1 * 4096);
    else             bv1 = *(const s16x8*)(bg + g1 * 64);
    ac0 = __builtin_amdgcn_mfma_f32_16x16x32_bf16(a0, bv0, ac0, 0, 0, 0);
    ac1 = __builtin_amdgcn_mfma_f32_16x16x32_bf16(a1, bv1, ac1, 0, 0, 0);
  }
  f32x4 acc = ac0 + ac1;

  // ---- gates exchange: gatesL[cd(64)][row(36 pad)] fp32 (proven) ----
  *(f32x4*)(gatesL + (size_t)cd * 36 + wm * 16 + lg * 4) = acc;
  __syncthreads();

  // ---- cell update: thread = (hc=tid&15, row=tid>>4) ----
  {
    const int hc = tid & 15, row = tid >> 4;
    float g0 = gatesL[(size_t)(0 * 16 + hc) * 36 + row];
    float g1 = gatesL[(size_t)(1 * 16 + hc) * 36 + row];
    float g2 = gatesL[(size_t)(2 * 16 + hc) * 36 + row];
    float g3 = gatesL[(size_t)(3 * 16 + hc) * 36 + row];
    float ig = sigf(g0 + b0);
    float fg = sigf(g1 + b1);
    float cg = fmaxf(g2 + b2, 0.0f);
    float og = sigf(g3 + b3);
    float cn = fg * cst + ig * cg;
    cst = cn;
    float h = og * tanhf_fast(cn);
    u32 hb = (u32)f2bf(h);
    int rowg = i32b + row;
    u64 a0 = (u64)(wrH + ((size_t)rowg * H_ + colg) * 2);
    asm volatile("global_store_short %0, %1, off sc0 sc1" :: "v"(a0), "v"(hb) : "memory");
    if (LAYER == 1) {                      // nt: no L2 write-allocate pollution
      u64 a1 = (u64)((char*)out + (((size_t)rowg * T_ + t) * H_ + colg) * 4);
      asm volatile("global_store_dword %0, %1, off nt" :: "v"(a1), "v"(h) : "memory");
    }
    if (t == T_ - 1) {
      out[HN_BASE_ + ((size_t)LAYER * 64 + rowg) * H_ + colg] = h;
      out[CN_BASE_ + ((size_t)LAYER * 64 + rowg) * H_ + colg] = cn;
    }
  }
}

__global__ __launch_bounds__(NTHR_, 1) void lstm_persist(
    const u16* __restrict__ xT, const u16* __restrict__ Wb0, const u16* __restrict__ Wb1,
    char* __restrict__ ring0, char* __restrict__ ring1, const float* __restrict__ bias,
    u32* __restrict__ sync, float* __restrict__ out)
{
  __shared__ __align__(16) char ldsRaw[161792];   // A(66560) + gates(9216) + wlds(86016)
  as3_char* ldsA = (as3_char*)ldsRaw;
  const int tid = threadIdx.x;
  const int bid = blockIdx.x;
  const int layer = bid >> 7, i = (bid >> 6) & 1, j = bid & 63;
  const int i32b = i * 32;
  const int K = layer ? 2048 : 1536;
  float* gatesL = (float*)(ldsRaw + 66560);
  as3_char* wlds = (as3_char*)(ldsRaw + 75776);
  const char* wbg = layer ? ((const char*)Wb1 + (size_t)j * 64 * 2048 * 2)
                          : ((const char*)Wb0 + (size_t)j * 64 * 1536 * 2);

  // ---- one-time: stage jj<21 weight slices into LDS (quad-swizzled) ----
  {
    const int nch = 64 * 21 * 4;
    for (int c = tid; c < nch; c += NTHR_) {
      int cd = c / 84;
      int r  = c - cd * 84;
      int jj = r >> 2, lg = r & 3;
      i32x4 v = *(const i32x4*)(wbg + ((size_t)cd * K + jj * 32 + lg * 8) * 2);
      *(as3_i32x4*)(wlds + (size_t)jj * 4096 + cd * 64 + ((lg ^ ((cd >> 1) & 3)) << 4)) = v;
    }
  }
  __syncthreads();

  const int colg = j * 16 + (tid & 15);
  float b0, b1, b2, b3;
  {
    const float* bb = bias + layer * 4096;
    b0 = bb[colg]; b1 = bb[1024 + colg]; b2 = bb[2048 + colg]; b3 = bb[3072 + colg];
  }
  float cst = 0.f;

  for (int s = 0; s <= T_; ++s) {
    const int m0 = s % NRING_;
    const int m1 = (s + 1) % NRING_;
    const int mm = (s >= 1) ? (s - 1) % NRING_ : 0;
    if (layer == 0) {
      if (s < T_)
        phase<0>(s, i32b, tid, xT, wbg,
                 ring0 + (size_t)m0 * RSLOT_, nullptr,
                 ring0 + (size_t)m1 * RSLOT_,
                 b0, b1, b2, b3, colg, cst, out, ldsA, gatesL, wlds);
    } else {
      if (s >= 1)
        phase<1>(s - 1, i32b, tid, xT, wbg,
                 ring0 + (size_t)m0 * RSLOT_, ring1 + (size_t)mm * RSLOT_,
                 ring1 + (size_t)m0 * RSLOT_,
                 b0, b1, b2, b3, colg, cst, out, ldsA, gatesL, wlds);
    }
    // ---- split direct-poll barrier (round-14 proven) ----
    VMW(0);                                  // drain data stores (incl. sc0sc1/nt)
    __syncthreads();
    if (tid == 0)
      __hip_atomic_store(sync + (size_t)bid * 32, (u32)(s + 1),
                         __ATOMIC_RELAXED, __HIP_MEMORY_SCOPE_AGENT);
    {
      const u32 tgtL1 = layer ? (u32)(s + 1)
                              : (u32)((s + 1 > 64) ? (s + 1 - 64) : 0);
      if (tid < 128) {
        const int grp = tid >> 6;
        const int jp  = tid & 63;
        const u32 tgt = grp ? tgtL1 : (u32)(s + 1);
        if (tgt) {
          u32* slot = sync + ((size_t)(grp * 128 + i * 64 + jp)) * 32;
          while (__hip_atomic_load(slot, __ATOMIC_RELAXED,
                                   __HIP_MEMORY_SCOPE_AGENT) < tgt)
            __builtin_amdgcn_s_sleep(2);
        }
      }
      __syncthreads();
    }
  }
}

// ============================ host launch ============================

extern "C" void kernel_launch(void* const* d_in, const int* in_sizes, int n_in,
                              void* d_out, int out_size, void* d_ws, size_t ws_size,
                              hipStream_t stream)
{
  const float* x    = (const float*)d_in[0];
  const float* Wih0 = (const float*)d_in[1];
  const float* bih0 = (const float*)d_in[2];
  const float* Whh0 = (const float*)d_in[3];
  const float* bhh0 = (const float*)d_in[4];
  const float* Wih1 = (const float*)d_in[5];
  const float* bih1 = (const float*)d_in[6];
  const float* Whh1 = (const float*)d_in[7];
  const float* bhh1 = (const float*)d_in[8];

  char* ws = (char*)d_ws;
  u16* Wb0    = (u16*)(ws + WB0_OFF);
  u16* Wb1    = (u16*)(ws + WB1_OFF);
  u16* xT     = (u16*)(ws + XT_OFF);
  char* ring0 = ws + RING0_OFF;
  char* ring1 = ws + RING1_OFF;
  float* bias = (float*)(ws + BIAS_OFF);
  u32* sync   = (u32*)(ws + SYNC_OFF);
  float* out  = (float*)d_out;

  prep_misc<<<1024, 256, 0, stream>>>(bih0, bhh0, bih1, bhh1, bias,
                                      (u32*)ring0, (u32*)ring1, sync);
  prep_w<<<3584, 256, 0, stream>>>(Wih0, Whh0, Wih1, Whh1, Wb0, Wb1);
  prep_x<<<4096, 256, 0, stream>>>(x, xT);
  lstm_persist<<<NBLK_, NTHR_, 0, stream>>>(xT, Wb0, Wb1, ring0, ring1, bias, sync, out);
}